// Round 5
// baseline (661.444 us; speedup 1.0000x reference)
//
#include <hip/hip_runtime.h>
#include <hip/hip_bf16.h>
#include <cstdint>
#include <cstddef>

// Masked causal dense attention, B=8, Tq=Tv=2048, D=512, key==value.
// R5: 32x32x16 MFMA restructure (32 FLOP/LDS-byte vs 16) + raw-barrier pipeline
// with counted vmcnt; 8-wave blocks, k-split QK + LDS S-combine, in-register
// P fragments (cvt_pkrtz + shfl_xor(32)); padded sVT rows (bank-uniform b128).

#define TQ   2048
#define TV   2048
#define DIM  512
#define NB   8
#define NROW (NB * TQ)
#define NS   2

typedef _Float16 f16x8 __attribute__((ext_vector_type(8)));
typedef _Float16 f16x4 __attribute__((ext_vector_type(4)));
typedef _Float16 f16x2 __attribute__((ext_vector_type(2)));
typedef float    f32x4  __attribute__((ext_vector_type(4)));
typedef float    f32x16 __attribute__((ext_vector_type(16)));
typedef int      i32x4  __attribute__((ext_vector_type(4)));

// ---- mask dtype runtime detection (bool may arrive as u8 / i32 / i64 / f32) ----
__device__ __forceinline__ int mask_fmt(const void* qm) {
    const unsigned* p = (const unsigned*)qm;
    unsigned w0 = p[0];
    if (w0 & 0xFF00u) return 0;                  // u8
    unsigned w1 = p[1];
    if (w0 == 1u) return (w1 != 0u) ? 1 : 2;     // i32 vs i64
    return 3;                                     // f32
}
__device__ __forceinline__ bool mask_bit(const void* m, int fmt, size_t i) {
    if (fmt == 0) return ((const unsigned char*)m)[i] != 0;
    if (fmt == 1) return ((const int*)m)[i] != 0;
    if (fmt == 2) return ((const unsigned*)m)[2 * i] != 0;
    return ((const float*)m)[i] != 0.0f;
}

// global -> LDS DMA, 16B per lane; LDS dest = uniform base + lane*16 (linear)
__device__ __forceinline__ void gload_lds16(const void* g, void* l) {
    __builtin_amdgcn_global_load_lds(
        (const __attribute__((address_space(1))) unsigned int*)g,
        (__attribute__((address_space(3))) unsigned int*)l, 16, 0, 0);
}

// ---- V f32 -> wv f16 row-major + wvt f16 transposed [b][d][v] (64x64 LDS tiles) ----
__global__ __launch_bounds__(256)
void prep_v_kernel(const float* __restrict__ vf, _Float16* __restrict__ wv,
                   _Float16* __restrict__ wvt) {
    __shared__ float sT[64][65];
    int z   = blockIdx.x;
    int b   = z & 7;
    int tv0 = ((z >> 3) & 31) * 64;
    int d0  = (z >> 8) * 64;
    int tid = threadIdx.x;
    int vl  = tid >> 4;
    int dq  = (tid & 15) * 4;
#pragma unroll
    for (int i = 0; i < 4; ++i) {
        int v = vl + i * 16;
        f32x4 x = *(const f32x4*)(vf + ((size_t)b * TV + tv0 + v) * DIM + d0 + dq);
        f16x4 h;
#pragma unroll
        for (int j = 0; j < 4; ++j) { h[j] = (_Float16)x[j]; sT[v][dq + j] = x[j]; }
        *(f16x4*)(wv + ((size_t)b * TV + tv0 + v) * DIM + d0 + dq) = h;
    }
    __syncthreads();
    int dl = tid >> 4;
    int vq = (tid & 15) * 4;
#pragma unroll
    for (int i = 0; i < 4; ++i) {
        int d = dl + i * 16;
        f16x4 h;
#pragma unroll
        for (int j = 0; j < 4; ++j) h[j] = (_Float16)sT[vq + j][d];
        *(f16x4*)(wvt + ((size_t)b * DIM + d0 + d) * TV + tv0 + vq) = h;
    }
}

__global__ __launch_bounds__(512, 2)
void attn_kernel(const float* __restrict__ qf, const _Float16* __restrict__ wv,
                 const _Float16* __restrict__ wvt,
                 const void* __restrict__ qmask, const void* __restrict__ vmask,
                 _Float16* __restrict__ pacc, float* __restrict__ pml) {
    // sV[32 v][512 k] f16, 16B-chunk swizzle: LDS[v][c] = wv[v][c ^ (v&7)]
    __shared__ __align__(16) _Float16 sV[32 * 512];           // 32 KB
    // sVT: 512 d-rows x 80B (64B data + 16B pad) -> bank-uniform b128 reads
    __shared__ __align__(16) char sVT[512 * 80];              // 40 KB
    __shared__ float sS[8][32 * 32];                          // 32 KB S-partials
    __shared__ int sAct[4];

    const int tid  = threadIdx.x;
    const int lane = tid & 63;
    const int w    = tid >> 6;       // wave 0..7
    const int l31  = lane & 31;
    const int h    = lane >> 5;      // half-wave

    const int bid  = blockIdx.x;
    const int b    = bid & 7;            // batch -> XCD L2 locality
    const int g    = (bid >> 3) & 15;
    const int s    = bid >> 7;           // KV parity split

    const int qsel   = w >> 1;           // 0..3
    const int kslice = w & 1;            // QK k-half; also PV d-half
    const int qtile  = (qsel < 2) ? (2 * g + qsel) : (62 - 2 * g + (qsel - 2));
    const int qbase  = qtile * 32;
    const int qrow   = qbase + l31;
    const size_t qrowG = (size_t)b * TQ + qrow;

    const int fmt = mask_fmt(qmask);

    {   // q-tile active flags (before any DMA; plain __syncthreads OK here)
        bool qbit = mask_bit(qmask, fmt, qrowG);
        unsigned long long bal = __ballot(qbit);
        if (lane == 0 && kslice == 0) sAct[qsel] = (bal != 0ull);
    }
    __syncthreads();
    int tiles0 = 2 * g, tiles1 = 2 * g + 1, tiles2 = 62 - 2 * g, tiles3 = 63 - 2 * g;
    int bmax = -1;
    if (sAct[0]) bmax = max(bmax, tiles0);
    if (sAct[1]) bmax = max(bmax, tiles1);
    if (sAct[2]) bmax = max(bmax, tiles2);
    if (sAct[3]) bmax = max(bmax, tiles3);
    const bool waveActive = (sAct[qsel] != 0);
    const int bound = qtile;

    // ---- Q B-frags: lane holds Q[qbase+l31][kslice*256 + kst*16 + h*8 + j] ----
    f16x8 qreg[16];
    if (waveActive) {
#pragma unroll
        for (int kst = 0; kst < 16; ++kst) {
            const float* qp = qf + qrowG * DIM + kslice * 256 + kst * 16 + h * 8;
            f32x4 x0 = *(const f32x4*)qp;
            f32x4 x1 = *(const f32x4*)(qp + 4);
            f16x8 t;
#pragma unroll
            for (int j = 0; j < 4; ++j) { t[j] = (_Float16)x0[j]; t[4 + j] = (_Float16)x1[j]; }
            qreg[kst] = t;
        }
    }

    // ---- staging helpers (wave-uniform, all waves always participate) ----
    auto stage_sV = [&](int tt) {    // 4 loads/wave
        int vb2 = tt * 32;
#pragma unroll
        for (int k = 0; k < 4; ++k) {
            int vr = w * 4 + k;
            const _Float16* src = wv + ((size_t)b * TV + vb2 + vr) * DIM + ((lane ^ (vr & 7)) << 3);
            gload_lds16(src, (char*)sV + vr * 1024);
        }
    };
    auto stage_sVT = [&](int tt) {   // 5 loads/wave (80B rows, linear dst)
        int vb2 = tt * 32;
#pragma unroll
        for (int k = 0; k < 5; ++k) {
            int slot = k * 64 + lane;            // 0..319
            int dloc = slot / 5;
            int c    = slot - dloc * 5;
            int cs   = (c >= 4) ? 0 : c;         // pad slot: load anything valid
            const _Float16* src = wvt + ((size_t)b * DIM + w * 64 + dloc) * TV + vb2 + cs * 8;
            gload_lds16(src, sVT + w * 5120 + k * 1024);
        }
    };

    f32x16 acc[8];
#pragma unroll
    for (int dt = 0; dt < 8; ++dt) acc[dt] = (f32x16)(0.f);
    float m_run = -3.0e38f, l_run = 0.0f;

    // prologue: stage tile t0 = s into both buffers
    stage_sV(s);
    stage_sVT(s);
    asm volatile("s_waitcnt vmcnt(5)" ::: "memory");   // sV(t0) landed (own)
    __builtin_amdgcn_s_barrier();                      // block-wide; sVT(t0): 5 in flight

    for (int t = s; t <= bmax; t += NS) {
        const int vb = t * 32;
        unsigned mw = (unsigned)__ballot(mask_bit(vmask, fmt, (size_t)b * TV + vb + l31));
        if (mw == 0u) break;                           // block-uniform
        const bool act = waveActive && (t <= bound);
        int tn = t + NS; if (tn > bmax) tn = bmax;

        // === QK phase: S^T-partial = V[.,kslice] x Q^T[kslice,.] ===
        f32x16 S = (f32x16)(0.f);
        if (act) {
#pragma unroll
            for (int kst = 0; kst < 16; ++kst) {
                int cw = kslice * 32 + kst * 2 + h;    // wanted 16B chunk of row
                f16x8 a = *(const f16x8*)((const char*)sV + l31 * 1024 + ((cw ^ (l31 & 7)) << 4));
                S = __builtin_amdgcn_mfma_f32_32x32x16_f16(a, qreg[kst], S, 0, 0, 0);
            }
            // write S-partial: [v][q] f32, 2 lanes/bank (free)
#pragma unroll
            for (int r = 0; r < 16; ++r) {
                int vl = (r & 3) + 8 * (r >> 2) + 4 * h;
                sS[w][vl * 32 + l31] = S[r];
            }
        }
        asm volatile("s_waitcnt lgkmcnt(0)" ::: "memory");
        __builtin_amdgcn_s_barrier();                  // B1: sV reads + S writes done
        stage_sV(tn);                                  // next sV in flight (+4)

        f16x8 fragA, fragB;
        if (act) {
            // combine partner partial -> full S (bit-identical on both waves)
            float p[16];
            float tm = -3.0e38f;
#pragma unroll
            for (int r = 0; r < 16; ++r) {
                int vl = (r & 3) + 8 * (r >> 2) + 4 * h;
                float x = S[r] + sS[w ^ 1][vl * 32 + l31];
                bool valid = ((vb + vl) <= qrow) && ((mw >> vl) & 1u);
                x = valid ? x : (x - 1e9f);
                p[r] = x;
                tm = fmaxf(tm, x);
            }
            tm = fmaxf(tm, __shfl_xor(tm, 32, 64));    // full-row max (v split across h)
            if (!__all(tm <= m_run + 8.0f)) {          // defer-max (T13)
                float mn = fmaxf(m_run, tm);
                float rr = __expf(m_run - mn);
                l_run *= rr;
#pragma unroll
                for (int dt = 0; dt < 8; ++dt) acc[dt] *= rr;
                m_run = mn;
            }
            float ps = 0.0f;
#pragma unroll
            for (int r = 0; r < 16; ++r) { p[r] = __expf(p[r] - m_run); ps += p[r]; }
            ps += __shfl_xor(ps, 32, 64);
            l_run += ps;

            // P -> B-frags in-register: pk pairs + cross-half shfl reconstruction
            int pk[8];
#pragma unroll
            for (int i = 0; i < 8; ++i)
                pk[i] = __builtin_bit_cast(int, __builtin_amdgcn_cvt_pkrtz(p[2 * i], p[2 * i + 1]));
            int x0 = __shfl_xor(pk[0], 32, 64), x1 = __shfl_xor(pk[1], 32, 64);
            int x2 = __shfl_xor(pk[2], 32, 64), x3 = __shfl_xor(pk[3], 32, 64);
            int x4 = __shfl_xor(pk[4], 32, 64), x5 = __shfl_xor(pk[5], 32, 64);
            int x6 = __shfl_xor(pk[6], 32, 64), x7 = __shfl_xor(pk[7], 32, 64);
            i32x4 fa, fb;
            fa[0] = h ? x2 : pk[0];  fa[1] = h ? x3 : pk[1];   // j=0..3 : v = h*8+0..3
            fa[2] = h ? pk[2] : x0;  fa[3] = h ? pk[3] : x1;   // j=4..7 : v = h*8+4..7
            fb[0] = h ? x6 : pk[4];  fb[1] = h ? x7 : pk[5];
            fb[2] = h ? pk[6] : x4;  fb[3] = h ? pk[7] : x5;
            fragA = __builtin_bit_cast(f16x8, fa);
            fragB = __builtin_bit_cast(f16x8, fb);
        }
        asm volatile("s_waitcnt vmcnt(4)" ::: "memory");   // sVT(t) landed (own)
        __builtin_amdgcn_s_barrier();                      // B2: sVT(t) ready block-wide

        // === PV phase: out^T[d][q] += VT x P^T, wave's d-half ===
        if (act) {
#pragma unroll
            for (int dt = 0; dt < 8; ++dt) {
                const char* rowp = sVT + (kslice * 256 + dt * 32 + l31) * 80;
                f16x8 a0 = *(const f16x8*)(rowp + h * 16);
                acc[dt] = __builtin_amdgcn_mfma_f32_32x32x16_f16(a0, fragA, acc[dt], 0, 0, 0);
                f16x8 a1 = *(const f16x8*)(rowp + 32 + h * 16);
                acc[dt] = __builtin_amdgcn_mfma_f32_32x32x16_f16(a1, fragB, acc[dt], 0, 0, 0);
            }
        }
        __builtin_amdgcn_s_barrier();                      // B3: PV reads done block-wide
        stage_sVT(tn);                                     // next sVT in flight (+5)
        asm volatile("s_waitcnt vmcnt(5)" ::: "memory");   // sV(t+NS) landed (own)
        __builtin_amdgcn_s_barrier();                      // B4: sV(t+NS) ready block-wide
    }
    asm volatile("s_waitcnt vmcnt(0) lgkmcnt(0)" ::: "memory");

    // ---- epilogue: normalized f16 partials + (m,l) ----
    float inv = (l_run > 0.f) ? (1.0f / l_run) : 0.0f;
    _Float16* pb = pacc + ((size_t)s * NROW + qrowG) * DIM;
#pragma unroll
    for (int dt = 0; dt < 8; ++dt) {
#pragma unroll
        for (int gb = 0; gb < 4; ++gb) {
            f16x4 hh;
#pragma unroll
            for (int j = 0; j < 4; ++j) hh[j] = (_Float16)(acc[dt][gb * 4 + j] * inv);
            int d = kslice * 256 + dt * 32 + gb * 8 + 4 * h;
            *(f16x4*)(pb + d) = hh;
        }
    }
    if (kslice == 0 && h == 0) {
        size_t mi = ((size_t)s * NROW + qrowG) * 2;
        pml[mi]     = m_run;
        pml[mi + 1] = l_run;
    }
}

__global__ __launch_bounds__(256)
void combine_kernel(const _Float16* __restrict__ pacc, const float* __restrict__ pml,
                    const void* __restrict__ qmask, float* __restrict__ out) {
    int gid = blockIdx.x * 256 + threadIdx.x;
    int row = gid >> 7;
    int c   = (gid & 127) * 4;
    if (row >= NROW) return;
    float ms[NS], ls[NS];
    float m = -3.0e38f;
#pragma unroll
    for (int s2 = 0; s2 < NS; ++s2) {
        ms[s2] = pml[((size_t)s2 * NROW + row) * 2];
        ls[s2] = pml[((size_t)s2 * NROW + row) * 2 + 1];
        if (ls[s2] > 0.f) m = fmaxf(m, ms[s2]);
    }
    float wgt[NS], L = 0.f;
#pragma unroll
    for (int s2 = 0; s2 < NS; ++s2) {
        wgt[s2] = (ls[s2] > 0.f) ? __expf(ms[s2] - m) * ls[s2] : 0.f;
        L += wgt[s2];
    }
    int fmt = mask_fmt(qmask);
    bool qb = mask_bit(qmask, fmt, (size_t)row);
    float inv = (L > 0.f && qb) ? (1.0f / L) : 0.f;
    f32x4 o = (f32x4){0.f, 0.f, 0.f, 0.f};
#pragma unroll
    for (int s2 = 0; s2 < NS; ++s2) {
        if (wgt[s2] > 0.f) {
            f16x4 hh = *(const f16x4*)(pacc + ((size_t)s2 * NROW + row) * DIM + c);
#pragma unroll
            for (int j = 0; j < 4; ++j) o[j] += wgt[s2] * (float)hh[j];
        }
    }
    o *= inv;
    *(f32x4*)(out + (size_t)row * DIM + c) = o;
}

extern "C" void kernel_launch(void* const* d_in, const int* in_sizes, int n_in,
                              void* d_out, int out_size, void* d_ws, size_t ws_size,
                              hipStream_t stream) {
    const float* q = (const float*)d_in[0];
    const float* v = (const float*)d_in[1];
    const void* qm = d_in[2];
    const void* vm = d_in[3];
    float* out = (float*)d_out;

    const size_t wvB   = (size_t)NB * TV * DIM * sizeof(_Float16);     // 16.78 MB
    const size_t wvtB  = wvB;                                          // 16.78 MB
    const size_t paccB = (size_t)NS * NROW * DIM * sizeof(_Float16);   // 33.55 MB
    const size_t pmlB  = (size_t)NS * NROW * 2 * sizeof(float);        // 0.26 MB

    if (ws_size < wvB + wvtB + paccB + pmlB) {   // not expected (R4 proved ~84MB OK)
        hipMemsetAsync(d_out, 0, (size_t)out_size * sizeof(float), stream);
        return;
    }
    _Float16* wv   = (_Float16*)d_ws;
    _Float16* wvt  = (_Float16*)((char*)d_ws + wvB);
    _Float16* pacc = (_Float16*)((char*)d_ws + wvB + wvtB);
    float*    pml  = (float*)((char*)d_ws + wvB + wvtB + paccB);

    prep_v_kernel<<<dim3(2048), dim3(256), 0, stream>>>(v, wv, wvt);
    attn_kernel<<<dim3(NB * 16 * NS), dim3(512), 0, stream>>>(q, wv, wvt, qm, vm, pacc, pml);
    combine_kernel<<<dim3((NROW * 128) / 256), dim3(256), 0, stream>>>(pacc, pml, qm, out);
}